// Round 24
// baseline (317.067 us; speedup 1.0000x reference)
//
#include <hip/hip_runtime.h>
#include <stdint.h>

#define Hdim 112
#define Wdim 112
#define CIN  128
#define COUT 128
#define NB   32
#define HW   (Hdim*Wdim)   // 12544
#define HALO_W 114
#define ROWSTR (HALO_W*16)          // 1824 B per ring row
#define SLOT_STRIDE (4*ROWSTR)      // 7296 B per ci-16 slot (4-row ring)
#define IT 2                        // 2-row slabs per block

// ws layout:
//   Wi8 : int8 [9][COUT][CIN]  @ 0   (147456 B)  weight signs as +-1
// (pkx eliminated — packing fused into binconv's stage phase)

typedef int   v4i __attribute__((ext_vector_type(4)));
typedef float v4f __attribute__((ext_vector_type(4)));

__global__ void pack_w_i8(const float* __restrict__ W, char* __restrict__ Wi8) {
    int t = blockIdx.x * blockDim.x + threadIdx.x;
    if (t >= COUT * 9) return;
    int co = t / 9, tap = t % 9;
    const float* wp = W + (size_t)co * CIN * 9 + tap;
    uint32_t* dst = (uint32_t*)(Wi8 + ((size_t)tap * COUT + co) * CIN);
    #pragma unroll
    for (int c4 = 0; c4 < 32; c4++) {
        uint32_t word = 0;
        #pragma unroll
        for (int j = 0; j < 4; j++) {
            uint32_t neg = __float_as_uint(wp[(size_t)(c4 * 4 + j) * 9]) >> 31;
            word |= (neg ? 0xFFu : 0x01u) << (8 * j);
        }
        dst[c4] = word;
    }
}

// spread low 4 bits into 4 bytes: bit=0 -> 0x01 (+1), bit=1 -> 0xFF (-1)
__device__ __forceinline__ uint32_t expand4(uint32_t b) {
    uint32_t s = ((b & 0xFu) * 0x00204081u) & 0x01010101u;
    return 0x01010101u ^ (s * 0xFEu);
}

// stage one halo pixel directly from f32 x (sign-extract + expand to i8).
// Reads 128 NT scalar f32 (coalesced 256B/instr across lanes: consecutive
// threads = consecutive w). OOB -> true i8 zeros (exact padding).
__device__ __forceinline__ void stage_px_f32(const float* __restrict__ xn,
                                             char* halo, int h, int w,
                                             int ring, int c) {
    bool valid = (h >= 0) && (h < Hdim) && (w >= 0) && (w < Wdim);
    uint32_t keep = valid ? 0xFFFFFFFFu : 0u;
    int hc = min(max(h, 0), Hdim - 1);
    int wc = min(max(w, 0), Wdim - 1);
    const float* p = xn + hc * Wdim + wc;
    unsigned base = (unsigned)(ring * ROWSTR + c * 16);
    #pragma unroll
    for (int sl = 0; sl < 8; sl++) {      // slot sl = ci 16sl..16sl+15
        uint32_t q = 0;
        #pragma unroll
        for (int j = 0; j < 16; j++) {
            float v = __builtin_nontemporal_load(p + (size_t)(sl * 16 + j) * HW);
            q |= (__float_as_uint(v) >> 31) << j;
        }
        uint4 ov;
        ov.x = expand4(q)       & keep;
        ov.y = expand4(q >> 4)  & keep;
        ov.z = expand4(q >> 8)  & keep;
        ov.w = expand4(q >> 12) & keep;
        *reinterpret_cast<uint4*>(&halo[sl * SLOT_STRIDE + base]) = ov;
    }
}

// implicit-GEMM binconv via i8 MFMA — R22 ring structure, PACKING FUSED.
// R23 postmortem: 16x16 shape caused 64B store scatter (WRITE 320MB) and
// A-fetch thrash (FETCH 48MB) -> reverted to R22's proven 32x32 geometry
// (wave = 32co x 224px, 112-AGPR acc, compiler tap-prefetch, NT stores,
// mod-4 halo ring, lgkmcnt-only barriers so stores fly across restage).
// NEW: the serial 40us pack_x kernel is eliminated — the stage phase
// reads f32 x directly (1.5x = 314MB NT, ring-amortized) and packs to
// i8 in LDS. binconv's HBM stream becomes ~520MB (~83us) which it can
// absorb; total drops by the pack_x phase. absmax-0 semantics unchanged.
__global__ __launch_bounds__(256, 2) void binconv_mfma(
    const float* __restrict__ x, const char* __restrict__ Wi8,
    const float* __restrict__ bias, float* __restrict__ out) {
    __shared__ char halo[8 * SLOT_STRIDE];   // 58368 B

    int tid = threadIdx.x;
    int hy = blockIdx.x;                     // 0..27 (4 output rows per block)
    int n  = blockIdx.y;
    int h0 = hy * (2 * IT);

    const float* xn = x + (size_t)n * CIN * HW;

    // initial stage: image rows h0-1 .. h0+2 -> ring rows 0..3
    for (int i = tid; i < 4 * HALO_W; i += 256) {
        int r = i / HALO_W, c = i - r * HALO_W;
        stage_px_f32(xn, halo, h0 - 1 + r, c - 1, r, c);
    }

    int wid = tid >> 6, l = tid & 63;
    int al = l & 31, ah = l >> 5;
    int cobase = wid * 32;                   // wave's 32-co slice

    // per-pt: pixel P = pt*32+al of the 2x112 slab tile
    int colb[7], rsel[7], wcol[7];
    #pragma unroll
    for (int pt = 0; pt < 7; pt++) {
        int P = pt * 32 + al;
        rsel[pt] = (P >= Wdim) ? 1 : 0;
        wcol[pt] = P - rsel[pt] * Wdim;
        colb[pt] = wcol[pt] * 16 + ah * SLOT_STRIDE;
    }

    const char* wA = Wi8 + ((size_t)cobase + al) * CIN + ah * 16;
    float* ob = out + (size_t)n * COUT * HW;

    __syncthreads();

    #pragma unroll
    for (int s = 0; s < IT; s++) {
        const int hs = h0 + 2 * s;

        v16i_decl:;
        typedef int v16i __attribute__((ext_vector_type(16)));
        v16i acc[7];
        #pragma unroll
        for (int pt = 0; pt < 7; pt++)
            #pragma unroll
            for (int i = 0; i < 16; i++) acc[pt][i] = 0;

        v4i A[4];
        #pragma unroll
        for (int kk = 0; kk < 4; kk++)
            A[kk] = *reinterpret_cast<const v4i*>(wA + kk * 32);

        #pragma unroll
        for (int tap = 0; tap < 9; tap++) {
            v4i N[4];
            if (tap < 8) {                   // compiler-scheduled prefetch (R14/R22-proven)
                const char* wt = wA + (size_t)(tap + 1) * COUT * CIN;
                #pragma unroll
                for (int kk = 0; kk < 4; kk++)
                    N[kk] = *reinterpret_cast<const v4i*>(wt + kk * 32);
            }
            const int dy = tap / 3, dx = tap % 3;
            int po[7];
            #pragma unroll
            for (int pt = 0; pt < 7; pt++)
                po[pt] = colb[pt] + (((2 * s + dy + rsel[pt]) & 3) * ROWSTR) + dx * 16;
            #pragma unroll
            for (int kk = 0; kk < 4; kk++) {
                v4i b[7];
                #pragma unroll
                for (int pt = 0; pt < 7; pt++)
                    b[pt] = *reinterpret_cast<const v4i*>(&halo[kk * 2 * SLOT_STRIDE + po[pt]]);
                #pragma unroll
                for (int pt = 0; pt < 7; pt++)
                    acc[pt] = __builtin_amdgcn_mfma_i32_32x32x32_i8(A[kk], b[pt], acc[pt], 0, 0, 0);
            }
            if (tap < 8) {
                #pragma unroll
                for (int kk = 0; kk < 4; kk++) A[kk] = N[kk];
            }
        }

        // epilogue: C col=lane&31 (px), row=(reg&3)+8*(reg>>2)+4*ah (co).
        // NT stores issued, NOT drained — they fly across the restage barriers.
        #pragma unroll
        for (int reg = 0; reg < 16; reg++) {
            int co = cobase + (reg & 3) + ((reg >> 2) << 3) + (ah << 2);
            float bv = bias[co];
            #pragma unroll
            for (int pt = 0; pt < 7; pt++) {
                size_t off = (size_t)co * HW + (size_t)(hs + rsel[pt]) * Wdim + wcol[pt];
                __builtin_nontemporal_store((float)acc[pt][reg] + bv, &ob[off]);
            }
        }

        if (s + 1 < IT) {
            // barrier WITHOUT vmcnt drain: only LDS ops must settle.
            asm volatile("s_waitcnt lgkmcnt(0)" ::: "memory");
            __builtin_amdgcn_s_barrier();
            __builtin_amdgcn_sched_barrier(0);
            // restage 2 new rows (hs+3, hs+4) into the 2 oldest ring rows
            for (int i = tid; i < 2 * HALO_W; i += 256) {
                int r = i / HALO_W, c = i - r * HALO_W;
                stage_px_f32(xn, halo, hs + 3 + r, c - 1, (2 * s + r) & 3, c);
            }
            asm volatile("s_waitcnt lgkmcnt(0)" ::: "memory");
            __builtin_amdgcn_s_barrier();
            __builtin_amdgcn_sched_barrier(0);
        }
    }
}

extern "C" void kernel_launch(void* const* d_in, const int* in_sizes, int n_in,
                              void* d_out, int out_size, void* d_ws, size_t ws_size,
                              hipStream_t stream) {
    const float* x = (const float*)d_in[0];
    const float* W = (const float*)d_in[1];
    const float* b = (const float*)d_in[2];
    float* out = (float*)d_out;
    char* Wi8 = (char*)d_ws;

    pack_w_i8<<<dim3((COUT * 9 + 255) / 256), dim3(256), 0, stream>>>(W, Wi8);
    binconv_mfma<<<dim3(Hdim / (2 * IT), NB), dim3(256), 0, stream>>>(x, Wi8, b, out);
}

// Round 25
// 123.956 us; speedup vs baseline: 2.5579x; 2.5579x over previous
//
#include <hip/hip_runtime.h>
#include <stdint.h>

#define Hdim 112
#define Wdim 112
#define CIN  128
#define COUT 128
#define NB   32
#define HW   (Hdim*Wdim)   // 12544
#define HALO_W 114
#define ROWSTR (HALO_W*16)          // 1824 B per ring row
#define SLOT_STRIDE (4*ROWSTR)      // 7296 B per ci-16 slot (4-row ring)
#define IT 2                        // 2-row slabs per block

// ws layout:
//   Wi8 : int8 [9][COUT][CIN]  @ 0        (147456 B)  weight signs as +-1
//   pkx : uint4[NB*HW]         @ 147456   (6.4 MB)    packed activation sign bits

typedef int   v4i __attribute__((ext_vector_type(4)));
typedef int  v16i __attribute__((ext_vector_type(16)));
typedef float v4f __attribute__((ext_vector_type(4)));

__global__ void pack_w_i8(const float* __restrict__ W, char* __restrict__ Wi8) {
    int t = blockIdx.x * blockDim.x + threadIdx.x;
    if (t >= COUT * 9) return;
    int co = t / 9, tap = t % 9;
    const float* wp = W + (size_t)co * CIN * 9 + tap;
    uint32_t* dst = (uint32_t*)(Wi8 + ((size_t)tap * COUT + co) * CIN);
    #pragma unroll
    for (int c4 = 0; c4 < 32; c4++) {
        uint32_t word = 0;
        #pragma unroll
        for (int j = 0; j < 4; j++) {
            uint32_t neg = __float_as_uint(wp[(size_t)(c4 * 4 + j) * 9]) >> 31;
            word |= (neg ? 0xFFu : 0x01u) << (8 * j);
        }
        dst[c4] = word;
    }
}

// each thread packs 4 consecutive pixels across all 128 channels.
// x is 205 MB single-use -> nontemporal loads keep it out of L2/L3.
__global__ __launch_bounds__(256) void pack_x_kernel(const float* __restrict__ x,
                                                     uint4* __restrict__ pkx) {
    int gid = blockIdx.x * blockDim.x + threadIdx.x;   // 0..100351
    int n = gid / (HW / 4);
    int p = (gid - n * (HW / 4)) * 4;
    const float* xp = x + (size_t)n * CIN * HW + p;
    uint32_t m[4][4] = {{0,0,0,0},{0,0,0,0},{0,0,0,0},{0,0,0,0}};
    #pragma unroll
    for (int c = 0; c < CIN; c++) {
        v4f v = __builtin_nontemporal_load(
            reinterpret_cast<const v4f*>(xp + (size_t)c * HW));
        int q = c >> 5, s = c & 31;
        m[0][q] |= (__float_as_uint(v.x) >> 31) << s;
        m[1][q] |= (__float_as_uint(v.y) >> 31) << s;
        m[2][q] |= (__float_as_uint(v.z) >> 31) << s;
        m[3][q] |= (__float_as_uint(v.w) >> 31) << s;
    }
    uint4* op = pkx + (size_t)n * HW + p;
    #pragma unroll
    for (int j = 0; j < 4; j++)
        op[j] = make_uint4(m[j][0], m[j][1], m[j][2], m[j][3]);
}

// spread low 4 bits into 4 bytes: bit=0 -> 0x01 (+1), bit=1 -> 0xFF (-1)
__device__ __forceinline__ uint32_t expand4(uint32_t b) {
    uint32_t s = ((b & 0xFu) * 0x00204081u) & 0x01010101u;
    return 0x01010101u ^ (s * 0xFEu);
}

// stage one halo pixel (image row h, col w) into ring row `ring`, halo col c
__device__ __forceinline__ void stage_px(const uint4* __restrict__ pkx, char* halo,
                                         int n, int h, int w, int ring, int c) {
    bool valid = (h >= 0) && (h < Hdim) && (w >= 0) && (w < Wdim);
    uint32_t keep = valid ? 0xFFFFFFFFu : 0u;
    int hc = min(max(h, 0), Hdim - 1);
    int wc = min(max(w, 0), Wdim - 1);
    uint4 bits = pkx[(size_t)n * HW + hc * Wdim + wc];
    uint32_t src[4] = {bits.x, bits.y, bits.z, bits.w};
    unsigned base = (unsigned)(ring * ROWSTR + c * 16);
    #pragma unroll
    for (int sl = 0; sl < 8; sl++) {      // slot sl = ci 16sl..16sl+15
        uint32_t q = src[sl >> 1] >> ((sl & 1) * 16);
        uint4 ov;
        ov.x = expand4(q)       & keep;
        ov.y = expand4(q >> 4)  & keep;
        ov.z = expand4(q >> 8)  & keep;
        ov.w = expand4(q >> 12) & keep;
        *reinterpret_cast<uint4*>(&halo[sl * SLOT_STRIDE + base]) = ov;
    }
}

// implicit-GEMM binconv via i8 MFMA — R22 configuration (proven best: 124.2us).
// Structure: R14's full-width 2-row slab geometry (wave = 32co x 224px,
// 112-AGPR acc, compiler-scheduled next-tap A prefetch, NT scalar stores)
// + mod-4 halo row ring (stage 4 rows once, +2 per slab, IT=2 slabs/block)
// + lgkmcnt-only barrier waits so slab0's NT stores stay in flight across
// the restage (no vmcnt(0) drain at barriers).
// R24 lesson: fusing pack_x in (scalar NT x-reads at 2 waves/SIMD) was 2.5x
// worse — the separate high-occupancy pack_x kernel is the right split.
// OOB pixels staged as true i8 zeros -> exact zero padding (absmax 0.0).
__global__ __launch_bounds__(256, 2) void binconv_mfma(
    const uint4* __restrict__ pkx, const char* __restrict__ Wi8,
    const float* __restrict__ bias, float* __restrict__ out) {
    __shared__ char halo[8 * SLOT_STRIDE];   // 58368 B

    int tid = threadIdx.x;
    int hy = blockIdx.x;                     // 0..27 (4 output rows per block)
    int n  = blockIdx.y;
    int h0 = hy * (2 * IT);

    // initial stage: image rows h0-1 .. h0+2 -> ring rows 0..3
    for (int i = tid; i < 4 * HALO_W; i += 256) {
        int r = i / HALO_W, c = i - r * HALO_W;
        stage_px(pkx, halo, n, h0 - 1 + r, c - 1, r, c);
    }

    int wid = tid >> 6, l = tid & 63;
    int al = l & 31, ah = l >> 5;
    int cobase = wid * 32;                   // wave's 32-co slice

    // per-pt: pixel P = pt*32+al of the 2x112 slab tile
    int colb[7], rsel[7], wcol[7];
    #pragma unroll
    for (int pt = 0; pt < 7; pt++) {
        int P = pt * 32 + al;
        rsel[pt] = (P >= Wdim) ? 1 : 0;
        wcol[pt] = P - rsel[pt] * Wdim;
        colb[pt] = wcol[pt] * 16 + ah * SLOT_STRIDE;
    }

    const char* wA = Wi8 + ((size_t)cobase + al) * CIN + ah * 16;
    float* ob = out + (size_t)n * COUT * HW;

    __syncthreads();

    #pragma unroll
    for (int s = 0; s < IT; s++) {
        const int hs = h0 + 2 * s;

        v16i acc[7];
        #pragma unroll
        for (int pt = 0; pt < 7; pt++)
            #pragma unroll
            for (int i = 0; i < 16; i++) acc[pt][i] = 0;

        v4i A[4];
        #pragma unroll
        for (int kk = 0; kk < 4; kk++)
            A[kk] = *reinterpret_cast<const v4i*>(wA + kk * 32);

        #pragma unroll
        for (int tap = 0; tap < 9; tap++) {
            v4i N[4];
            if (tap < 8) {                   // compiler-scheduled prefetch (R14-proven)
                const char* wt = wA + (size_t)(tap + 1) * COUT * CIN;
                #pragma unroll
                for (int kk = 0; kk < 4; kk++)
                    N[kk] = *reinterpret_cast<const v4i*>(wt + kk * 32);
            }
            const int dy = tap / 3, dx = tap % 3;
            int po[7];
            #pragma unroll
            for (int pt = 0; pt < 7; pt++)
                po[pt] = colb[pt] + (((2 * s + dy + rsel[pt]) & 3) * ROWSTR) + dx * 16;
            #pragma unroll
            for (int kk = 0; kk < 4; kk++) {
                v4i b[7];
                #pragma unroll
                for (int pt = 0; pt < 7; pt++)
                    b[pt] = *reinterpret_cast<const v4i*>(&halo[kk * 2 * SLOT_STRIDE + po[pt]]);
                #pragma unroll
                for (int pt = 0; pt < 7; pt++)
                    acc[pt] = __builtin_amdgcn_mfma_i32_32x32x32_i8(A[kk], b[pt], acc[pt], 0, 0, 0);
            }
            if (tap < 8) {
                #pragma unroll
                for (int kk = 0; kk < 4; kk++) A[kk] = N[kk];
            }
        }

        // epilogue: C col=lane&31 (px), row=(reg&3)+8*(reg>>2)+4*ah (co).
        // NT stores issued, NOT drained — they fly across the restage barriers.
        #pragma unroll
        for (int reg = 0; reg < 16; reg++) {
            int co = cobase + (reg & 3) + ((reg >> 2) << 3) + (ah << 2);
            float bv = bias[co];
            #pragma unroll
            for (int pt = 0; pt < 7; pt++) {
                size_t off = (size_t)co * HW + (size_t)(hs + rsel[pt]) * Wdim + wcol[pt];
                __builtin_nontemporal_store((float)acc[pt][reg] + bv, &ob[off]);
            }
        }

        if (s + 1 < IT) {
            // barrier WITHOUT vmcnt drain: only LDS ops must settle.
            asm volatile("s_waitcnt lgkmcnt(0)" ::: "memory");
            __builtin_amdgcn_s_barrier();
            __builtin_amdgcn_sched_barrier(0);
            // restage 2 new rows (hs+3, hs+4) into the 2 oldest ring rows
            for (int i = tid; i < 2 * HALO_W; i += 256) {
                int r = i / HALO_W, c = i - r * HALO_W;
                stage_px(pkx, halo, n, hs + 3 + r, c - 1, (2 * s + r) & 3, c);
            }
            asm volatile("s_waitcnt lgkmcnt(0)" ::: "memory");
            __builtin_amdgcn_s_barrier();
            __builtin_amdgcn_sched_barrier(0);
        }
    }
}

extern "C" void kernel_launch(void* const* d_in, const int* in_sizes, int n_in,
                              void* d_out, int out_size, void* d_ws, size_t ws_size,
                              hipStream_t stream) {
    const float* x = (const float*)d_in[0];
    const float* W = (const float*)d_in[1];
    const float* b = (const float*)d_in[2];
    float* out = (float*)d_out;
    char* ws = (char*)d_ws;
    char*  Wi8 = ws;
    uint4* pkx = (uint4*)(ws + 147456);

    pack_w_i8<<<dim3((COUT * 9 + 255) / 256), dim3(256), 0, stream>>>(W, Wi8);
    pack_x_kernel<<<dim3(NB * HW / 4 / 256), dim3(256), 0, stream>>>(x, pkx);
    binconv_mfma<<<dim3(Hdim / (2 * IT), NB), dim3(256), 0, stream>>>(pkx, Wi8, b, out);
}